// Round 3
// baseline (160.596 us; speedup 1.0000x reference)
//
#include <hip/hip_runtime.h>
#include <hip/hip_bf16.h>

#define CH 384
#define HH 56
#define WW 56
#define HW (HH*WW)      // 3136 = 49*64
#define NN 16
#define YPITCH 392      // fused-fallback LDS pitch
#define PIXPAD 64

typedef __attribute__((ext_vector_type(4))) float f32x4;
typedef __attribute__((ext_vector_type(8))) short bf16x8;

// Prepared weights
__device__ float          g_wdw_eff[CH * 9];   // depthwise: u*mx exact fp32, [o][tap]
__device__ __hip_bfloat16 g_wpw_u[CH * CH];    // pointwise: ternary u exact bf16, [co][ci]
__device__ float          g_mx_pw;             // pointwise scale (epilogue multiply)

__global__ __launch_bounds__(1024) void prep_kernel(const float* __restrict__ wdw,
                                                    const float* __restrict__ wpw) {
    const int tid = threadIdx.x;

    // ---- depthwise per-channel quant (threads 0..383) ----
    if (tid < CH) {
        const float* w = wdw + tid * 9;
        float asum = 0.f;
        #pragma unroll
        for (int t = 0; t < 9; ++t) asum += fabsf(w[t]);
        const float m  = asum / 9.0f;
        const float mx = fmaxf(m, 1e-5f);
        const float sc = 1.0f / mx;
        #pragma unroll
        for (int t = 0; t < 9; ++t) {
            float u = rintf(w[t] * sc);          // jnp.round == RNE
            u = fminf(1.f, fmaxf(-1.f, u));
            g_wdw_eff[tid * 9 + t] = u * mx;     // exact product
        }
    }

    // ---- pointwise global mean|w|: float4 loads, 4 indep fp64 accumulators ----
    double s0 = 0.0, s1 = 0.0, s2 = 0.0, s3 = 0.0;
    for (int i = tid * 4; i < CH * CH; i += 4096) {
        const float4 v = *reinterpret_cast<const float4*>(wpw + i);
        s0 += (double)fabsf(v.x); s1 += (double)fabsf(v.y);
        s2 += (double)fabsf(v.z); s3 += (double)fabsf(v.w);
    }
    double s = (s0 + s1) + (s2 + s3);
    #pragma unroll
    for (int off = 32; off > 0; off >>= 1) s += __shfl_down(s, off, 64);

    __shared__ double sred[16];
    if ((tid & 63) == 0) sred[tid >> 6] = s;
    __syncthreads();

    __shared__ float s_scale;
    if (tid == 0) {
        double tot = 0.0;
        #pragma unroll
        for (int i = 0; i < 16; ++i) tot += sred[i];
        const float mean = (float)(tot / (double)(CH * CH));
        const float mx   = fmaxf(mean, 1e-5f);
        g_mx_pw = mx;
        s_scale = 1.0f / mx;
    }
    __syncthreads();

    const float scale = s_scale;
    for (int base = tid * 8; base < CH * CH; base += 8192) {
        const float4 a = *reinterpret_cast<const float4*>(wpw + base);
        const float4 b = *reinterpret_cast<const float4*>(wpw + base + 4);
        const float vin[8] = {a.x, a.y, a.z, a.w, b.x, b.y, b.z, b.w};
        bf16x8 uo;
        #pragma unroll
        for (int t = 0; t < 8; ++t) {
            float u = rintf(vin[t] * scale);
            u = fminf(1.f, fmaxf(-1.f, u));
            __hip_bfloat16 h = __float2bfloat16(u);     // {-1,0,1} exact in bf16
            uo[t] = *reinterpret_cast<short*>(&h);
        }
        *reinterpret_cast<bf16x8*>(g_wpw_u + base) = uo;
    }
}

// ---------- kernel 1: depthwise -> y[n][pix][ci] bf16 (transposed via LDS) ----------
__global__ __launch_bounds__(256) void dw_kernel(const float* __restrict__ x,
                                                 __hip_bfloat16* __restrict__ y) {
    __shared__ __hip_bfloat16 ylds[WW * CH];   // 43008 B, [w][ci], XOR-swizzled

    const int n = blockIdx.x / HH, h = blockIdx.x % HH;
    const float* xn = x + (size_t)n * CH * HW;

    for (int u = threadIdx.x; u < CH * 7; u += 256) {
        const int ci = u / 7;
        const int wc = u % 7;
        const int w0 = wc * 8;
        const float* xp = xn + (size_t)ci * HW;
        const float* wd = g_wdw_eff + ci * 9;
        float acc[8] = {0.f, 0.f, 0.f, 0.f, 0.f, 0.f, 0.f, 0.f};
        #pragma unroll
        for (int dy = -1; dy <= 1; ++dy) {
            const int hh = h + dy;
            if (hh < 0 || hh >= HH) continue;       // zero pad rows
            const float* row = xp + hh * WW;
            const float4 a = *reinterpret_cast<const float4*>(row + w0);
            const float4 b = *reinterpret_cast<const float4*>(row + w0 + 4);
            const float left  = (w0 > 0)       ? row[w0 - 1] : 0.f;
            const float right = (w0 + 8 < WW)  ? row[w0 + 8] : 0.f;
            const float xv[10] = {left, a.x, a.y, a.z, a.w, b.x, b.y, b.z, b.w, right};
            #pragma unroll
            for (int dx = 0; dx < 3; ++dx) {
                const float wv = wd[(dy + 1) * 3 + dx];
                #pragma unroll
                for (int j = 0; j < 8; ++j) acc[j] += xv[j + dx] * wv;
            }
        }
        // swizzled transpose store: elem = w*CH + ci, elem ^= ((w>>3)&7)<<3
        const int sw = (wc & 7) << 3;               // w>>3 == wc for w in this chunk
        #pragma unroll
        for (int j = 0; j < 8; ++j)
            ylds[(((w0 + j) * CH + ci)) ^ sw] = __float2bfloat16(acc[j]);
    }
    __syncthreads();

    // coalesced dump: global y is LINEAR [pix][ci]; un-swizzle on LDS read
    __hip_bfloat16* yb = y + ((size_t)n * HW + (size_t)h * WW) * CH;
    for (int c = threadIdx.x; c < WW * CH / 8; c += 256) {
        const int e  = c * 8;
        const int w  = e / CH;
        const int se = e ^ (((w >> 3) & 7) << 3);
        *reinterpret_cast<bf16x8*>(yb + e) =
            *reinterpret_cast<const bf16x8*>(&ylds[se]);
    }
}

// ---------- kernel 2: pointwise GEMM, no LDS, B-fragments direct from global ----------
__global__ __launch_bounds__(512) void pw_kernel(const __hip_bfloat16* __restrict__ y,
                                                 float* __restrict__ out) {
    const int n  = blockIdx.x / 49;
    const int pt = blockIdx.x % 49;                 // 64-pixel tile (3136 = 49*64 exact)
    const int wv   = threadIdx.x >> 6;
    const int lane = threadIdx.x & 63;
    const int lr   = lane & 15;
    const int lk   = lane >> 4;

    const __hip_bfloat16* yb = y + ((size_t)n * HW + (size_t)pt * 64) * CH;

    f32x4 acc[3][4];
    #pragma unroll
    for (int i = 0; i < 3; ++i)
        #pragma unroll
        for (int j = 0; j < 4; ++j) acc[i][j] = (f32x4){0.f, 0.f, 0.f, 0.f};

    for (int k0 = 0; k0 < CH; k0 += 32) {
        bf16x8 bfr[4];
        #pragma unroll
        for (int j = 0; j < 4; ++j)
            bfr[j] = *reinterpret_cast<const bf16x8*>(
                yb + (size_t)(16 * j + lr) * CH + k0 + 8 * lk);
        #pragma unroll
        for (int i = 0; i < 3; ++i) {
            const int co = (wv + 8 * i) * 16 + lr;
            const bf16x8 afr = *reinterpret_cast<const bf16x8*>(
                g_wpw_u + (size_t)co * CH + k0 + 8 * lk);
            #pragma unroll
            for (int j = 0; j < 4; ++j)
                acc[i][j] = __builtin_amdgcn_mfma_f32_16x16x32_bf16(afr, bfr[j], acc[i][j], 0, 0, 0);
        }
    }

    // D layout: col(lane&15)=pix, row((lane>>4)*4+reg)=co  [verified round 2]
    const float s = g_mx_pw;
    float* ob = out + (size_t)n * CH * HW + (size_t)pt * 64;
    #pragma unroll
    for (int j = 0; j < 4; ++j) {
        const int px = 16 * j + lr;
        #pragma unroll
        for (int i = 0; i < 3; ++i) {
            const int co0 = (wv + 8 * i) * 16 + lk * 4;
            #pragma unroll
            for (int r = 0; r < 4; ++r)
                ob[(size_t)(co0 + r) * HW + px] = acc[i][j][r] * s;
        }
    }
}

// ---------- fallback: round-2 fused kernel (used only if ws too small) ----------
__global__ __launch_bounds__(512, 4) void fused_kernel(const float* __restrict__ x,
                                                       float* __restrict__ out) {
    __shared__ __attribute__((aligned(16))) __hip_bfloat16 ylds[PIXPAD * YPITCH];

    const int blk = blockIdx.x;
    const int n = blk / HH, h = blk % HH;
    const float* xn = x + (size_t)n * CH * HW;

    for (int unit = threadIdx.x; unit < CH * 8; unit += 512) {
        const int ci = unit >> 3;
        const int w0 = (unit & 7) * 7;
        const float* xp = xn + (size_t)ci * HW;
        const float* wd = g_wdw_eff + ci * 9;
        float acc[7] = {0.f, 0.f, 0.f, 0.f, 0.f, 0.f, 0.f};
        #pragma unroll
        for (int dy = -1; dy <= 1; ++dy) {
            const int hh = h + dy;
            if (hh < 0 || hh >= HH) continue;
            const float* row = xp + hh * WW;
            float xv[9];
            #pragma unroll
            for (int t = 0; t < 9; ++t) {
                const int c = w0 - 1 + t;
                xv[t] = (c >= 0 && c < WW) ? row[c] : 0.0f;
            }
            #pragma unroll
            for (int dx = 0; dx < 3; ++dx) {
                const float wv = wd[(dy + 1) * 3 + dx];
                #pragma unroll
                for (int j = 0; j < 7; ++j) acc[j] += xv[j + dx] * wv;
            }
        }
        #pragma unroll
        for (int j = 0; j < 7; ++j)
            ylds[(w0 + j) * YPITCH + ci] = __float2bfloat16(acc[j]);
    }
    __syncthreads();

    const int wv   = threadIdx.x >> 6;
    const int lane = threadIdx.x & 63;
    const int lr   = lane & 15;
    const int lk   = lane >> 4;

    f32x4 acc[3][4];
    #pragma unroll
    for (int i = 0; i < 3; ++i)
        #pragma unroll
        for (int j = 0; j < 4; ++j) acc[i][j] = (f32x4){0.f, 0.f, 0.f, 0.f};

    for (int k0 = 0; k0 < CH; k0 += 32) {
        bf16x8 bfr[4];
        #pragma unroll
        for (int j = 0; j < 4; ++j)
            bfr[j] = *reinterpret_cast<const bf16x8*>(
                &ylds[(16 * j + lr) * YPITCH + k0 + 8 * lk]);
        #pragma unroll
        for (int i = 0; i < 3; ++i) {
            const int co = (wv + 8 * i) * 16 + lr;
            bf16x8 afr = *reinterpret_cast<const bf16x8*>(
                &g_wpw_u[(size_t)co * CH + k0 + 8 * lk]);
            #pragma unroll
            for (int j = 0; j < 4; ++j)
                acc[i][j] = __builtin_amdgcn_mfma_f32_16x16x32_bf16(afr, bfr[j], acc[i][j], 0, 0, 0);
        }
    }

    const float s = g_mx_pw;
    float* obase = out + (size_t)n * CH * HW + (size_t)h * WW;
    #pragma unroll
    for (int j = 0; j < 4; ++j) {
        const int pix = 16 * j + lr;
        if (pix >= WW) continue;
        #pragma unroll
        for (int i = 0; i < 3; ++i) {
            const int co0 = (wv + 8 * i) * 16 + lk * 4;
            #pragma unroll
            for (int r = 0; r < 4; ++r)
                obase[(size_t)(co0 + r) * HW + pix] = acc[i][j][r] * s;
        }
    }
}

extern "C" void kernel_launch(void* const* d_in, const int* in_sizes, int n_in,
                              void* d_out, int out_size, void* d_ws, size_t ws_size,
                              hipStream_t stream) {
    const float* x    = (const float*)d_in[0];   // (16,384,56,56)
    const float* w_dw = (const float*)d_in[1];   // (384,1,3,3)
    const float* w_pw = (const float*)d_in[2];   // (384,384,1,1)
    float* out = (float*)d_out;

    prep_kernel<<<1, 1024, 0, stream>>>(w_dw, w_pw);

    const size_t y_bytes = (size_t)NN * HW * CH * sizeof(__hip_bfloat16);  // 38.5 MB
    if (ws_size >= y_bytes) {
        __hip_bfloat16* y = (__hip_bfloat16*)d_ws;
        dw_kernel<<<NN * HH, 256, 0, stream>>>(x, y);
        pw_kernel<<<NN * 49, 512, 0, stream>>>(y, out);
    } else {
        fused_kernel<<<NN * HH, 512, 0, stream>>>(x, out);
    }
}

// Round 4
// 86.993 us; speedup vs baseline: 1.8461x; 1.8461x over previous
//
#include <hip/hip_runtime.h>
#include <hip/hip_bf16.h>

#define CH 384
#define HH 56
#define WW 56
#define HW (HH*WW)
#define NN 16
#define YPITCH 392      // LDS pitch: 384 + 8 (784 B/row; proven round 2)

typedef __attribute__((ext_vector_type(4))) float f32x4;
typedef __attribute__((ext_vector_type(8))) short bf16x8;

// Prepared weights
__device__ float          g_wdw_eff[CH * 9];   // depthwise: u*mx exact fp32, [o][tap]
__device__ __hip_bfloat16 g_wpw_u[CH * CH];    // pointwise: ternary u exact bf16, [co][ci]
__device__ float          g_mx_pw;             // pointwise scale (epilogue multiply)

// ---------- prep stage A: deterministic per-block |w| partial sums ----------
__global__ __launch_bounds__(256) void partial_kernel(const float* __restrict__ wpw,
                                                      double* __restrict__ part) {
    const int t = threadIdx.x;
    const int base = blockIdx.x * 1536;
    double s = 0.0;
    #pragma unroll
    for (int k = 0; k < 6; ++k) s += (double)fabsf(wpw[base + t + k * 256]);
    #pragma unroll
    for (int off = 32; off > 0; off >>= 1) s += __shfl_down(s, off, 64);
    __shared__ double sred[4];
    if ((t & 63) == 0) sred[t >> 6] = s;
    __syncthreads();
    if (t == 0) {
        double tot = ((sred[0] + sred[1]) + sred[2]) + sred[3];
        part[blockIdx.x] = tot;
    }
}

// ---------- prep stage B: finalize scale (in-order, deterministic) + quantize ----------
__global__ __launch_bounds__(512) void quant_kernel(const float* __restrict__ wdw,
                                                    const float* __restrict__ wpw,
                                                    const double* __restrict__ part) {
    const int t = threadIdx.x;
    __shared__ double pl[96];
    __shared__ float s_scale, s_mx;
    if (t < 96) pl[t] = part[t];
    __syncthreads();
    if (t == 0) {
        double tot = 0.0;
        #pragma unroll
        for (int i = 0; i < 96; ++i) tot += pl[i];   // fixed order
        const float mean = (float)(tot / (double)(CH * CH));
        const float mx   = fmaxf(mean, 1e-5f);
        s_mx = mx;
        s_scale = 1.0f / mx;
    }
    __syncthreads();
    const float scale = s_scale;

    // wpw slice: 36 blocks * 512 threads * 8 = 147456 exact
    const int base = blockIdx.x * 4096 + t * 8;
    const float4 a = *reinterpret_cast<const float4*>(wpw + base);
    const float4 b = *reinterpret_cast<const float4*>(wpw + base + 4);
    const float vin[8] = {a.x, a.y, a.z, a.w, b.x, b.y, b.z, b.w};
    bf16x8 uo;
    #pragma unroll
    for (int k = 0; k < 8; ++k) {
        float u = rintf(vin[k] * scale);             // jnp.round == RNE
        u = fminf(1.f, fmaxf(-1.f, u));
        __hip_bfloat16 h = __float2bfloat16(u);      // {-1,0,1} exact in bf16
        uo[k] = *reinterpret_cast<short*>(&h);
    }
    *reinterpret_cast<bf16x8*>(g_wpw_u + base) = uo;

    if (blockIdx.x == 0) {
        if (t == 0) g_mx_pw = s_mx;
        if (t < CH) {
            const float* w = wdw + t * 9;
            float asum = 0.f;
            #pragma unroll
            for (int k = 0; k < 9; ++k) asum += fabsf(w[k]);
            const float m   = asum / 9.0f;
            const float mxd = fmaxf(m, 1e-5f);
            const float scd = 1.0f / mxd;
            #pragma unroll
            for (int k = 0; k < 9; ++k) {
                float u = rintf(w[k] * scd);
                u = fminf(1.f, fmaxf(-1.f, u));
                g_wdw_eff[t * 9 + k] = u * mxd;      // exact product
            }
        }
    }
}

// ---------- fallback single-block prep (only if ws_size < 768 B) ----------
__global__ __launch_bounds__(1024) void prep_kernel(const float* __restrict__ wdw,
                                                    const float* __restrict__ wpw) {
    const int tid = threadIdx.x;
    if (tid < CH) {
        const float* w = wdw + tid * 9;
        float asum = 0.f;
        #pragma unroll
        for (int k = 0; k < 9; ++k) asum += fabsf(w[k]);
        const float m  = asum / 9.0f;
        const float mx = fmaxf(m, 1e-5f);
        const float sc = 1.0f / mx;
        #pragma unroll
        for (int k = 0; k < 9; ++k) {
            float u = rintf(w[k] * sc);
            u = fminf(1.f, fmaxf(-1.f, u));
            g_wdw_eff[tid * 9 + k] = u * mx;
        }
    }
    double s0 = 0.0, s1 = 0.0, s2 = 0.0, s3 = 0.0;
    for (int i = tid * 4; i < CH * CH; i += 4096) {
        const float4 v = *reinterpret_cast<const float4*>(wpw + i);
        s0 += (double)fabsf(v.x); s1 += (double)fabsf(v.y);
        s2 += (double)fabsf(v.z); s3 += (double)fabsf(v.w);
    }
    double s = (s0 + s1) + (s2 + s3);
    #pragma unroll
    for (int off = 32; off > 0; off >>= 1) s += __shfl_down(s, off, 64);
    __shared__ double sred[16];
    if ((tid & 63) == 0) sred[tid >> 6] = s;
    __syncthreads();
    __shared__ float s_scale;
    if (tid == 0) {
        double tot = 0.0;
        #pragma unroll
        for (int i = 0; i < 16; ++i) tot += sred[i];
        const float mean = (float)(tot / (double)(CH * CH));
        const float mx   = fmaxf(mean, 1e-5f);
        g_mx_pw = mx;
        s_scale = 1.0f / mx;
    }
    __syncthreads();
    const float scale = s_scale;
    for (int base = tid * 8; base < CH * CH; base += 8192) {
        const float4 a = *reinterpret_cast<const float4*>(wpw + base);
        const float4 b = *reinterpret_cast<const float4*>(wpw + base + 4);
        const float vin[8] = {a.x, a.y, a.z, a.w, b.x, b.y, b.z, b.w};
        bf16x8 uo;
        #pragma unroll
        for (int k = 0; k < 8; ++k) {
            float u = rintf(vin[k] * scale);
            u = fminf(1.f, fmaxf(-1.f, u));
            __hip_bfloat16 h = __float2bfloat16(u);
            uo[k] = *reinterpret_cast<short*>(&h);
        }
        *reinterpret_cast<bf16x8*>(g_wpw_u + base) = uo;
    }
}

// ---------- fused: depthwise -> y[pix][ci] bf16 LDS -> prefetched MFMA pointwise ----------
__global__ __launch_bounds__(512) void fused_kernel(const float* __restrict__ x,
                                                    float* __restrict__ out) {
    __shared__ __attribute__((aligned(16))) __hip_bfloat16 ylds[64 * YPITCH]; // 50176 B

    // XCD-aware swizzle: 896 = 8 XCDs x 112; h-adjacent blocks share x halo in L2
    const int bid  = blockIdx.x;
    const int orig = (bid & 7) * 112 + (bid >> 3);
    const int n = orig / HH, h = orig % HH;
    const float* xn = x + (size_t)n * CH * HW;

    // ---- phase 1: depthwise, vectorized loads (8-wide chunks, 7 per row) ----
    for (int u = threadIdx.x; u < CH * 7; u += 512) {
        const int ci = u / 7;
        const int wc = u % 7;
        const int w0 = wc * 8;
        const float* xp = xn + (size_t)ci * HW;
        const float* wd = g_wdw_eff + ci * 9;
        float acc[8] = {0.f, 0.f, 0.f, 0.f, 0.f, 0.f, 0.f, 0.f};
        #pragma unroll
        for (int dy = -1; dy <= 1; ++dy) {
            const int hh = h + dy;
            if (hh < 0 || hh >= HH) continue;            // zero pad rows
            const float* row = xp + hh * WW;
            const float4 va = *reinterpret_cast<const float4*>(row + w0);
            const float4 vb = *reinterpret_cast<const float4*>(row + w0 + 4);
            const float left  = (w0 > 0)      ? row[w0 - 1] : 0.f;
            const float right = (w0 + 8 < WW) ? row[w0 + 8] : 0.f;
            const float xv[10] = {left, va.x, va.y, va.z, va.w,
                                  vb.x, vb.y, vb.z, vb.w, right};
            #pragma unroll
            for (int dx = 0; dx < 3; ++dx) {
                const float wv = wd[(dy + 1) * 3 + dx];
                #pragma unroll
                for (int j = 0; j < 8; ++j) acc[j] += xv[j + dx] * wv;
            }
        }
        #pragma unroll
        for (int j = 0; j < 8; ++j)
            ylds[(w0 + j) * YPITCH + ci] = __float2bfloat16(acc[j]);  // transpose store
    }
    __syncthreads();

    // ---- phase 2: pointwise GEMM, 1-deep ping-pong prefetch ----
    const int wv   = threadIdx.x >> 6;
    const int lane = threadIdx.x & 63;
    const int lr   = lane & 15;
    const int lk   = lane >> 4;

    f32x4 acc[3][4];
    #pragma unroll
    for (int i = 0; i < 3; ++i)
        #pragma unroll
        for (int j = 0; j < 4; ++j) acc[i][j] = (f32x4){0.f, 0.f, 0.f, 0.f};

    const __hip_bfloat16* abase0 = g_wpw_u + (size_t)(wv * 16 + lr) * CH + 8 * lk;
    const __hip_bfloat16* lbase  = &ylds[lr * YPITCH + 8 * lk];

#define LOADB(dst, K) { \
    _Pragma("unroll") \
    for (int j = 0; j < 4; ++j) \
        dst[j] = *reinterpret_cast<const bf16x8*>(lbase + 16 * j * YPITCH + (K)); }
#define LOADA(dst, K) { \
    _Pragma("unroll") \
    for (int i = 0; i < 3; ++i) \
        dst[i] = *reinterpret_cast<const bf16x8*>(abase0 + (size_t)(8 * i * 16) * CH + (K)); }

    bf16x8 bcur[4], acur[3];
    LOADB(bcur, 0); LOADA(acur, 0);

    #pragma unroll
    for (int kk = 0; kk < 12; ++kk) {
        bf16x8 bnxt[4], anxt[3];
        if (kk < 11) { LOADB(bnxt, (kk + 1) * 32); LOADA(anxt, (kk + 1) * 32); }
        #pragma unroll
        for (int i = 0; i < 3; ++i)
            #pragma unroll
            for (int j = 0; j < 4; ++j)
                acc[i][j] = __builtin_amdgcn_mfma_f32_16x16x32_bf16(acur[i], bcur[j], acc[i][j], 0, 0, 0);
        if (kk < 11) {
            #pragma unroll
            for (int j = 0; j < 4; ++j) bcur[j] = bnxt[j];
            #pragma unroll
            for (int i = 0; i < 3; ++i) acur[i] = anxt[i];
        }
    }
#undef LOADB
#undef LOADA

    // ---- epilogue: D col(lane&15)=pix, row((lane>>4)*4+reg)=co ----
    const float s = g_mx_pw;
    float* obase = out + (size_t)n * CH * HW + (size_t)h * WW;
    #pragma unroll
    for (int j = 0; j < 4; ++j) {
        const int pix = 16 * j + lr;
        if (pix >= WW) continue;
        #pragma unroll
        for (int i = 0; i < 3; ++i) {
            const int co0 = (wv + 8 * i) * 16 + lk * 4;
            #pragma unroll
            for (int r = 0; r < 4; ++r)
                obase[(size_t)(co0 + r) * HW + pix] = acc[i][j][r] * s;
        }
    }
}

extern "C" void kernel_launch(void* const* d_in, const int* in_sizes, int n_in,
                              void* d_out, int out_size, void* d_ws, size_t ws_size,
                              hipStream_t stream) {
    const float* x    = (const float*)d_in[0];   // (16,384,56,56)
    const float* w_dw = (const float*)d_in[1];   // (384,1,3,3)
    const float* w_pw = (const float*)d_in[2];   // (384,384,1,1)
    float* out = (float*)d_out;

    if (ws_size >= 96 * sizeof(double)) {
        double* part = (double*)d_ws;
        partial_kernel<<<96, 256, 0, stream>>>(w_pw, part);
        quant_kernel<<<36, 512, 0, stream>>>(w_dw, w_pw, part);
    } else {
        prep_kernel<<<1, 1024, 0, stream>>>(w_dw, w_pw);
    }
    fused_kernel<<<NN * HH, 512, 0, stream>>>(x, out);
}

// Round 5
// 86.685 us; speedup vs baseline: 1.8526x; 1.0035x over previous
//
#include <hip/hip_runtime.h>
#include <hip/hip_bf16.h>

#define CH 384
#define HH 56
#define WW 56
#define HW (HH*WW)
#define NN 16

// XOR swizzle in bf16-element units: flips bits 3..5 of the in-row element
// offset. Reads (row=16j+lr): slot=(lr&7)^(lr>>3)^2j -> 2 lanes/slot (free).
// Writes (row=8wc+j, fixed ci): slot=j^wc -> 7 distinct slots (conflict-free).
#define ESWZ(row) (((((row) & 7) ^ (((row) >> 3) & 7))) << 3)

typedef __attribute__((ext_vector_type(4))) float f32x4;
typedef __attribute__((ext_vector_type(8))) short bf16x8;

// Prepared weights
__device__ float          g_wdw_eff[CH * 9];   // depthwise: u*mx exact fp32, [o][tap]
__device__ __hip_bfloat16 g_wpw_u[CH * CH];    // pointwise: ternary u exact bf16, [co][ci]
__device__ float          g_mx_pw;             // pointwise scale (epilogue multiply)

// ---------- prep stage A: deterministic per-block |w| partial sums ----------
__global__ __launch_bounds__(256) void partial_kernel(const float* __restrict__ wpw,
                                                      double* __restrict__ part) {
    const int t = threadIdx.x;
    const int base = blockIdx.x * 1536;
    double s = 0.0;
    #pragma unroll
    for (int k = 0; k < 6; ++k) s += (double)fabsf(wpw[base + t + k * 256]);
    #pragma unroll
    for (int off = 32; off > 0; off >>= 1) s += __shfl_down(s, off, 64);
    __shared__ double sred[4];
    if ((t & 63) == 0) sred[t >> 6] = s;
    __syncthreads();
    if (t == 0) {
        double tot = ((sred[0] + sred[1]) + sred[2]) + sred[3];
        part[blockIdx.x] = tot;
    }
}

// ---------- prep stage B: finalize scale (in-order, deterministic) + quantize ----------
__global__ __launch_bounds__(512) void quant_kernel(const float* __restrict__ wdw,
                                                    const float* __restrict__ wpw,
                                                    const double* __restrict__ part) {
    const int t = threadIdx.x;
    __shared__ double pl[96];
    __shared__ float s_scale, s_mx;
    if (t < 96) pl[t] = part[t];
    __syncthreads();
    if (t == 0) {
        double tot = 0.0;
        #pragma unroll
        for (int i = 0; i < 96; ++i) tot += pl[i];   // fixed order
        const float mean = (float)(tot / (double)(CH * CH));
        const float mx   = fmaxf(mean, 1e-5f);
        s_mx = mx;
        s_scale = 1.0f / mx;
    }
    __syncthreads();
    const float scale = s_scale;

    // wpw slice: 36 blocks * 512 threads * 8 = 147456 exact
    const int base = blockIdx.x * 4096 + t * 8;
    const float4 a = *reinterpret_cast<const float4*>(wpw + base);
    const float4 b = *reinterpret_cast<const float4*>(wpw + base + 4);
    const float vin[8] = {a.x, a.y, a.z, a.w, b.x, b.y, b.z, b.w};
    bf16x8 uo;
    #pragma unroll
    for (int k = 0; k < 8; ++k) {
        float u = rintf(vin[k] * scale);             // jnp.round == RNE
        u = fminf(1.f, fmaxf(-1.f, u));
        __hip_bfloat16 h = __float2bfloat16(u);      // {-1,0,1} exact in bf16
        uo[k] = *reinterpret_cast<short*>(&h);
    }
    *reinterpret_cast<bf16x8*>(g_wpw_u + base) = uo;

    if (blockIdx.x == 0) {
        if (t == 0) g_mx_pw = s_mx;
        if (t < CH) {
            const float* w = wdw + t * 9;
            float asum = 0.f;
            #pragma unroll
            for (int k = 0; k < 9; ++k) asum += fabsf(w[k]);
            const float m   = asum / 9.0f;
            const float mxd = fmaxf(m, 1e-5f);
            const float scd = 1.0f / mxd;
            #pragma unroll
            for (int k = 0; k < 9; ++k) {
                float u = rintf(w[k] * scd);
                u = fminf(1.f, fmaxf(-1.f, u));
                g_wdw_eff[t * 9 + k] = u * mxd;      // exact product
            }
        }
    }
}

// ---------- fallback single-block prep (only if ws_size < 768 B) ----------
__global__ __launch_bounds__(1024) void prep_kernel(const float* __restrict__ wdw,
                                                    const float* __restrict__ wpw) {
    const int tid = threadIdx.x;
    if (tid < CH) {
        const float* w = wdw + tid * 9;
        float asum = 0.f;
        #pragma unroll
        for (int k = 0; k < 9; ++k) asum += fabsf(w[k]);
        const float m  = asum / 9.0f;
        const float mx = fmaxf(m, 1e-5f);
        const float sc = 1.0f / mx;
        #pragma unroll
        for (int k = 0; k < 9; ++k) {
            float u = rintf(w[k] * sc);
            u = fminf(1.f, fmaxf(-1.f, u));
            g_wdw_eff[tid * 9 + k] = u * mx;
        }
    }
    double s0 = 0.0, s1 = 0.0, s2 = 0.0, s3 = 0.0;
    for (int i = tid * 4; i < CH * CH; i += 4096) {
        const float4 v = *reinterpret_cast<const float4*>(wpw + i);
        s0 += (double)fabsf(v.x); s1 += (double)fabsf(v.y);
        s2 += (double)fabsf(v.z); s3 += (double)fabsf(v.w);
    }
    double s = (s0 + s1) + (s2 + s3);
    #pragma unroll
    for (int off = 32; off > 0; off >>= 1) s += __shfl_down(s, off, 64);
    __shared__ double sred[16];
    if ((tid & 63) == 0) sred[tid >> 6] = s;
    __syncthreads();
    __shared__ float s_scale;
    if (tid == 0) {
        double tot = 0.0;
        #pragma unroll
        for (int i = 0; i < 16; ++i) tot += sred[i];
        const float mean = (float)(tot / (double)(CH * CH));
        const float mx   = fmaxf(mean, 1e-5f);
        g_mx_pw = mx;
        s_scale = 1.0f / mx;
    }
    __syncthreads();
    const float scale = s_scale;
    for (int base = tid * 8; base < CH * CH; base += 8192) {
        const float4 a = *reinterpret_cast<const float4*>(wpw + base);
        const float4 b = *reinterpret_cast<const float4*>(wpw + base + 4);
        const float vin[8] = {a.x, a.y, a.z, a.w, b.x, b.y, b.z, b.w};
        bf16x8 uo;
        #pragma unroll
        for (int k = 0; k < 8; ++k) {
            float u = rintf(vin[k] * scale);
            u = fminf(1.f, fmaxf(-1.f, u));
            __hip_bfloat16 h = __float2bfloat16(u);
            uo[k] = *reinterpret_cast<short*>(&h);
        }
        *reinterpret_cast<bf16x8*>(g_wpw_u + base) = uo;
    }
}

// ---------- fused: depthwise -> y[pix][ci] bf16 LDS (swizzled) -> MFMA pointwise ----------
// launch_bounds(512,4): explicit 128-reg budget so the ping-pong prefetch
// actually materializes (round 4: default heuristic chose VGPR=56, deleting it).
__global__ __launch_bounds__(512, 4) void fused_kernel(const float* __restrict__ x,
                                                       float* __restrict__ out) {
    __shared__ __attribute__((aligned(16))) __hip_bfloat16 ylds[64 * CH]; // 49152 B

    // XCD-aware swizzle: 896 = 8 XCDs x 112; h-adjacent blocks share x halo in L2
    const int bid  = blockIdx.x;
    const int orig = (bid & 7) * 112 + (bid >> 3);
    const int n = orig / HH, h = orig % HH;
    const float* xn = x + (size_t)n * CH * HW;

    // ---- phase 1: depthwise, vectorized loads (8-wide chunks, 7 per row) ----
    for (int u = threadIdx.x; u < CH * 7; u += 512) {
        const int ci = u / 7;
        const int wc = u % 7;
        const int w0 = wc * 8;
        const float* xp = xn + (size_t)ci * HW;
        const float* wd = g_wdw_eff + ci * 9;
        float acc[8] = {0.f, 0.f, 0.f, 0.f, 0.f, 0.f, 0.f, 0.f};
        #pragma unroll
        for (int dy = -1; dy <= 1; ++dy) {
            const int hh = h + dy;
            if (hh < 0 || hh >= HH) continue;            // zero pad rows
            const float* row = xp + hh * WW;
            const float4 va = *reinterpret_cast<const float4*>(row + w0);
            const float4 vb = *reinterpret_cast<const float4*>(row + w0 + 4);
            const float left  = (w0 > 0)      ? row[w0 - 1] : 0.f;
            const float right = (w0 + 8 < WW) ? row[w0 + 8] : 0.f;
            const float xv[10] = {left, va.x, va.y, va.z, va.w,
                                  vb.x, vb.y, vb.z, vb.w, right};
            #pragma unroll
            for (int dx = 0; dx < 3; ++dx) {
                const float wv = wd[(dy + 1) * 3 + dx];
                #pragma unroll
                for (int j = 0; j < 8; ++j) acc[j] += xv[j + dx] * wv;
            }
        }
        // transposed store, swizzled: row = w0+j (row&7==j, row>>3==wc)
        #pragma unroll
        for (int j = 0; j < 8; ++j)
            ylds[(w0 + j) * CH + (ci ^ ((j ^ wc) << 3))] = __float2bfloat16(acc[j]);
    }
    __syncthreads();

    // ---- phase 2: pointwise GEMM, 1-deep ping-pong prefetch (A: L2, B: LDS) ----
    const int wv   = threadIdx.x >> 6;
    const int lane = threadIdx.x & 63;
    const int lr   = lane & 15;
    const int lk   = lane >> 4;

    f32x4 acc[3][4];
    #pragma unroll
    for (int i = 0; i < 3; ++i)
        #pragma unroll
        for (int j = 0; j < 4; ++j) acc[i][j] = (f32x4){0.f, 0.f, 0.f, 0.f};

    const __hip_bfloat16* abase = g_wpw_u + (size_t)(wv * 16 + lr) * CH + 8 * lk;

    int bbase[4];   // LDS element base per px-tile row, swizzle precomputed
    int bswz[4];
    #pragma unroll
    for (int jj = 0; jj < 4; ++jj) {
        const int row = 16 * jj + lr;
        bbase[jj] = row * CH;
        bswz[jj]  = ESWZ(row);
    }
    const int colb = 8 * lk;

#define LOADB(dst, K) { \
    _Pragma("unroll") \
    for (int j = 0; j < 4; ++j) \
        dst[j] = *reinterpret_cast<const bf16x8*>( \
            &ylds[bbase[j] + (((K) + colb) ^ bswz[j])]); }
#define LOADA(dst, K) { \
    _Pragma("unroll") \
    for (int i = 0; i < 3; ++i) \
        dst[i] = *reinterpret_cast<const bf16x8*>(abase + (size_t)(i * 128) * CH + (K)); }

    bf16x8 bcur[4], acur[3];
    LOADA(acur, 0); LOADB(bcur, 0);

    #pragma unroll
    for (int kk = 0; kk < 12; ++kk) {
        bf16x8 bnxt[4], anxt[3];
        if (kk < 11) { LOADA(anxt, (kk + 1) * 32); LOADB(bnxt, (kk + 1) * 32); }
        #pragma unroll
        for (int i = 0; i < 3; ++i)
            #pragma unroll
            for (int j = 0; j < 4; ++j)
                acc[i][j] = __builtin_amdgcn_mfma_f32_16x16x32_bf16(acur[i], bcur[j], acc[i][j], 0, 0, 0);
        if (kk < 11) {
            #pragma unroll
            for (int j = 0; j < 4; ++j) bcur[j] = bnxt[j];
            #pragma unroll
            for (int i = 0; i < 3; ++i) acur[i] = anxt[i];
        }
    }
#undef LOADB
#undef LOADA

    // ---- epilogue: D col(lane&15)=pix, row((lane>>4)*4+reg)=co ----
    const float s = g_mx_pw;
    float* obase = out + (size_t)n * CH * HW + (size_t)h * WW;
    #pragma unroll
    for (int j = 0; j < 4; ++j) {
        const int pix = 16 * j + lr;
        if (pix >= WW) continue;
        #pragma unroll
        for (int i = 0; i < 3; ++i) {
            const int co0 = (wv + 8 * i) * 16 + lk * 4;
            #pragma unroll
            for (int r = 0; r < 4; ++r)
                obase[(size_t)(co0 + r) * HW + pix] = acc[i][j][r] * s;
        }
    }
}

extern "C" void kernel_launch(void* const* d_in, const int* in_sizes, int n_in,
                              void* d_out, int out_size, void* d_ws, size_t ws_size,
                              hipStream_t stream) {
    const float* x    = (const float*)d_in[0];   // (16,384,56,56)
    const float* w_dw = (const float*)d_in[1];   // (384,1,3,3)
    const float* w_pw = (const float*)d_in[2];   // (384,384,1,1)
    float* out = (float*)d_out;

    if (ws_size >= 96 * sizeof(double)) {
        double* part = (double*)d_ws;
        partial_kernel<<<96, 256, 0, stream>>>(w_pw, part);
        quant_kernel<<<36, 512, 0, stream>>>(w_dw, w_pw, part);
    } else {
        prep_kernel<<<1, 1024, 0, stream>>>(w_dw, w_pw);
    }
    fused_kernel<<<NN * HH, 512, 0, stream>>>(x, out);
}